// Round 1
// baseline (79.648 us; speedup 1.0000x reference)
//
#include <hip/hip_runtime.h>
#include <hip/hip_bf16.h>

// Problem constants (match the JAX reference exactly).
#define BATCH 4
#define NDIM  4096
#define A_CONST  (-0.565)
#define B_CONST  (4.0)
#define SQRT_PI  (1.772453851)

// exp(-(B*d/A)^2) = exp2( L * d*d ),  L = -(B/A)^2 * log2(e)
// Computed in double precision at compile time, truncated to float.
constexpr double K_D   = (B_CONST / A_CONST) * (B_CONST / A_CONST);   // 50.12138...
constexpr double LOG2E = 1.4426950408889634;
constexpr float  L_F   = (float)(-K_D * LOG2E);                        // ~ -72.30994

// Overall scale: (1/(A*sqrt(pi)))^2 / (B*N*N)  — the "+1" in dirac cancels in the diff.
constexpr double C2_D    = 1.0 / (A_CONST * A_CONST * SQRT_PI * SQRT_PI);
constexpr double NPAIRS  = (double)BATCH * (double)NDIM * (double)NDIM;
constexpr float  SCALE_F = (float)(C2_D / NPAIRS);

#define NTHREADS 256
#define JCH      256   // j-chunk per block (staged in LDS)

__global__ __launch_bounds__(NTHREADS)
void dirac_loss_kernel(const float* __restrict__ x,
                       const float* __restrict__ t,
                       float* __restrict__ out) {
    // Decompose block id: b, i-chunk, j-chunk
    constexpr int NIC = NDIM / NTHREADS;   // 16
    constexpr int NJC = NDIM / JCH;        // 16
    int bid = blockIdx.x;
    int b   = bid / (NIC * NJC);
    int r   = bid % (NIC * NJC);
    int ic  = r / NJC;
    int jc  = r % NJC;

    const float* xb = x + b * NDIM;
    const float* tb = t + b * NDIM;

    __shared__ float xj[JCH];
    __shared__ float tj[JCH];
    {
        int j = threadIdx.x;              // JCH == NTHREADS: one load each
        xj[j] = xb[jc * JCH + j];
        tj[j] = tb[jc * JCH + j];
    }
    __syncthreads();

    const int i  = ic * NTHREADS + threadIdx.x;
    const float xi = xb[i];
    const float ti = tb[i];

    float acc = 0.0f;
#pragma unroll 8
    for (int j = 0; j < JCH; ++j) {
        float dp = xi - xj[j];            // |.| irrelevant: we square it
        float dg = ti - tj[j];
        float ep = __builtin_amdgcn_exp2f(L_F * (dp * dp));
        float eg = __builtin_amdgcn_exp2f(L_F * (dg * dg));
        float d  = ep - eg;
        acc = fmaf(d, d, acc);
    }

    // Wave (64-lane) butterfly reduce, then cross-wave via LDS.
    for (int off = 32; off; off >>= 1)
        acc += __shfl_down(acc, off, 64);

    __shared__ float wsum[NTHREADS / 64];
    const int lane = threadIdx.x & 63;
    const int wid  = threadIdx.x >> 6;
    if (lane == 0) wsum[wid] = acc;
    __syncthreads();

    if (threadIdx.x == 0) {
        float s = wsum[0] + wsum[1] + wsum[2] + wsum[3];
        atomicAdd(out, s * SCALE_F);
    }
}

extern "C" void kernel_launch(void* const* d_in, const int* in_sizes, int n_in,
                              void* d_out, int out_size, void* d_ws, size_t ws_size,
                              hipStream_t stream) {
    const float* x = (const float*)d_in[0];   // input  [B, N] f32
    const float* t = (const float*)d_in[1];   // target [B, N] f32
    float* out = (float*)d_out;               // scalar f32

    // Harness poisons d_out with 0xAA before every launch — zero it (capture-safe).
    hipMemsetAsync(out, 0, sizeof(float), stream);

    constexpr int NIC = NDIM / NTHREADS;
    constexpr int NJC = NDIM / JCH;
    dim3 grid(BATCH * NIC * NJC);   // 1024 blocks
    dim3 block(NTHREADS);
    dirac_loss_kernel<<<grid, block, 0, stream>>>(x, t, out);
}

// Round 3
// 75.270 us; speedup vs baseline: 1.0582x; 1.0582x over previous
//
#include <hip/hip_runtime.h>
#include <hip/hip_bf16.h>

// Problem constants (match the JAX reference exactly).
#define BATCH 4
#define NDIM  4096
#define A_CONST  (-0.565)
#define B_CONST  (4.0)
#define SQRT_PI  (1.772453851)

// exp(-(B*d/A)^2) = exp2( L * d*d ),  L = -(B/A)^2 * log2(e)
constexpr double K_D   = (B_CONST / A_CONST) * (B_CONST / A_CONST);
constexpr double LOG2E = 1.4426950408889634;
constexpr float  L_F   = (float)(-K_D * LOG2E);      // ~ -72.30994

// Overall scale: (1/(A*sqrt(pi)))^2 / (B*N*N) — the "+1" in dirac cancels.
constexpr double C2_D    = 1.0 / (A_CONST * A_CONST * SQRT_PI * SQRT_PI);
constexpr double NPAIRS  = (double)BATCH * (double)NDIM * (double)NDIM;
constexpr float  SCALE_F = (float)(C2_D / NPAIRS);

#define NTHREADS 256
#define IPT      4                    // i's per thread
#define ICH      (NTHREADS * IPT)     // 1024 i per block
#define JCH      64                   // j per block
// grid = B * (N/ICH) * (N/JCH) = 4 * 4 * 64 = 1024 blocks
#define NBLOCKS  (BATCH * (NDIM / ICH) * (NDIM / JCH))

// Stage 1: per-block partial sums -> d_ws (no atomics: 1024 same-address
// device-scope atomicAdds were the R1 serialization suspect).
__global__ __launch_bounds__(NTHREADS)
void dirac_partial_kernel(const float* __restrict__ x,
                          const float* __restrict__ t,
                          float* __restrict__ partial) {
    constexpr int NIC = NDIM / ICH;   // 4
    constexpr int NJC = NDIM / JCH;   // 64
    const int bid = blockIdx.x;
    const int b   = bid / (NIC * NJC);
    const int r   = bid % (NIC * NJC);
    const int ic  = r / NJC;
    const int jc  = r % NJC;

    const float* xb = x + b * NDIM;
    const float* tb = t + b * NDIM;

    // L*(u - v)^2 = (L*u^2) + (-2L*u)*v + (L*v^2) = a_i + b_i*v_j + c_j
    __shared__ float sxj[JCH], scx[JCH], stj[JCH], sct[JCH];
    if (threadIdx.x < JCH) {
        const float xj = xb[jc * JCH + threadIdx.x];
        const float tj = tb[jc * JCH + threadIdx.x];
        sxj[threadIdx.x] = xj;
        scx[threadIdx.x] = L_F * xj * xj;
        stj[threadIdx.x] = tj;
        sct[threadIdx.x] = L_F * tj * tj;
    }
    __syncthreads();

    float ax[IPT], bxm[IPT], at[IPT], btm[IPT];
#pragma unroll
    for (int k = 0; k < IPT; ++k) {
        const int i = ic * ICH + k * NTHREADS + threadIdx.x;
        const float xi = xb[i];
        const float ti = tb[i];
        ax[k]  = L_F * xi * xi;
        bxm[k] = -2.0f * L_F * xi;
        at[k]  = L_F * ti * ti;
        btm[k] = -2.0f * L_F * ti;
    }

    float acc = 0.0f;
#pragma unroll 4
    for (int j = 0; j < JCH; ++j) {
        const float xj = sxj[j];
        const float cx = scx[j];
        const float tj = stj[j];
        const float ct = sct[j];
#pragma unroll
        for (int k = 0; k < IPT; ++k) {
            // 2 VALU + 1 trans per side; diff sub + acc fma
            const float ep = __builtin_amdgcn_exp2f(fmaf(bxm[k], xj, ax[k] + cx));
            const float eg = __builtin_amdgcn_exp2f(fmaf(btm[k], tj, at[k] + ct));
            const float d  = ep - eg;
            acc = fmaf(d, d, acc);
        }
    }

    // Wave (64-lane) butterfly reduce, then cross-wave via LDS.
    for (int off = 32; off; off >>= 1)
        acc += __shfl_down(acc, off, 64);

    __shared__ float wsum[NTHREADS / 64];
    const int lane = threadIdx.x & 63;
    const int wid  = threadIdx.x >> 6;
    if (lane == 0) wsum[wid] = acc;
    __syncthreads();

    if (threadIdx.x == 0)
        partial[bid] = wsum[0] + wsum[1] + wsum[2] + wsum[3];
}

// Stage 2: reduce NBLOCKS partials, write the scaled scalar (no memset needed).
__global__ __launch_bounds__(NTHREADS)
void dirac_final_kernel(const float* __restrict__ partial,
                        float* __restrict__ out) {
    float v = 0.0f;
#pragma unroll
    for (int k = 0; k < NBLOCKS / NTHREADS; ++k)
        v += partial[k * NTHREADS + threadIdx.x];

    for (int off = 32; off; off >>= 1)
        v += __shfl_down(v, off, 64);

    __shared__ float wsum[NTHREADS / 64];
    const int lane = threadIdx.x & 63;
    const int wid  = threadIdx.x >> 6;
    if (lane == 0) wsum[wid] = v;
    __syncthreads();

    if (threadIdx.x == 0)
        out[0] = (wsum[0] + wsum[1] + wsum[2] + wsum[3]) * SCALE_F;
}

extern "C" void kernel_launch(void* const* d_in, const int* in_sizes, int n_in,
                              void* d_out, int out_size, void* d_ws, size_t ws_size,
                              hipStream_t stream) {
    const float* x = (const float*)d_in[0];   // input  [B, N] f32
    const float* t = (const float*)d_in[1];   // target [B, N] f32
    float* out     = (float*)d_out;           // scalar f32
    float* partial = (float*)d_ws;            // NBLOCKS floats of scratch

    dirac_partial_kernel<<<dim3(NBLOCKS), dim3(NTHREADS), 0, stream>>>(x, t, partial);
    dirac_final_kernel<<<dim3(1), dim3(NTHREADS), 0, stream>>>(partial, out);
}

// Round 4
// 68.081 us; speedup vs baseline: 1.1699x; 1.1056x over previous
//
#include <hip/hip_runtime.h>
#include <hip/hip_bf16.h>

// Problem constants (match the JAX reference exactly).
#define BATCH 4
#define NDIM  4096
#define TILE  128
#define TT    (NDIM / TILE)            // 32 tiles per dim
#define TRI   (TT * (TT + 1) / 2)      // 528 upper-triangle tiles per batch
#define NBLOCKS (BATCH * TRI)          // 2112
#define NTHREADS 256

#define A_CONST  (-0.565)
#define B_CONST  (4.0)
#define SQRT_PI  (1.772453851)

// exp(-(B*d/A)^2) = exp2( L * d*d ),  L = -(B/A)^2 * log2(e)
constexpr double K_D   = (B_CONST / A_CONST) * (B_CONST / A_CONST);
constexpr double LOG2E = 1.4426950408889634;
constexpr float  L_F   = (float)(-K_D * LOG2E);      // ~ -72.30994

// Overall scale: (1/(A*sqrt(pi)))^2 / (B*N*N) — the "+1" in dirac cancels.
constexpr double C2_D    = 1.0 / (A_CONST * A_CONST * SQRT_PI * SQRT_PI);
constexpr double NPAIRS  = (double)BATCH * (double)NDIM * (double)NDIM;
constexpr float  SCALE_F = (float)(C2_D / NPAIRS);

// Stage 1: one 128x128 tile of the symmetric pair matrix per block.
// Only upper-triangle tiles are launched; off-diagonal tiles count x2
// (covers (i,j) and (j,i)), diagonal tiles computed in full at x1
// (the i==j diagonal contributes exactly 0). Halves the exp count.
__global__ __launch_bounds__(NTHREADS)
void dirac_partial_kernel(const float* __restrict__ x,
                          const float* __restrict__ t,
                          float* __restrict__ partial) {
    const int bid = blockIdx.x;
    const int b   = bid / TRI;
    int rr = bid % TRI;
    int ic = 0;                         // triangular index -> (ic, jc), jc >= ic
    while (rr >= TT - ic) { rr -= TT - ic; ++ic; }
    const int jc = ic + rr;

    const float* xb = x + b * NDIM;
    const float* tb = t + b * NDIM;

    // Per-j quad packed as float4 -> single broadcast ds_read_b128 in the loop.
    __shared__ float4 sj[TILE];
    if (threadIdx.x < TILE) {
        const float xj = xb[jc * TILE + threadIdx.x];
        const float tj = tb[jc * TILE + threadIdx.x];
        sj[threadIdx.x] = make_float4(xj, L_F * xj * xj, tj, L_F * tj * tj);
    }
    __syncthreads();

    // 256 threads over 128 i's: 2 threads per i, each takes half the j range.
    const int il = threadIdx.x & (TILE - 1);
    const int i  = ic * TILE + il;
    const float xi = xb[i];
    const float ti = tb[i];
    const float ax = L_F * xi * xi;          // L*(u-v)^2 = ax + bx*v + cx(v)
    const float bx = -2.0f * L_F * xi;
    const float at = L_F * ti * ti;
    const float bt = -2.0f * L_F * ti;

    const int jbase = (threadIdx.x >> 7) * (TILE / 2);   // 0 or 64, wave-uniform
    float acc = 0.0f;
#pragma unroll 8
    for (int jj = 0; jj < TILE / 2; ++jj) {
        const float4 v = sj[jbase + jj];     // broadcast, conflict-free
        const float ep = __builtin_amdgcn_exp2f(fmaf(bx, v.x, ax + v.y));
        const float eg = __builtin_amdgcn_exp2f(fmaf(bt, v.z, at + v.w));
        const float d  = ep - eg;
        acc = fmaf(d, d, acc);
    }

    // Block reduce 256 -> 1.
    for (int off = 32; off; off >>= 1)
        acc += __shfl_down(acc, off, 64);
    __shared__ float wsum[NTHREADS / 64];
    if ((threadIdx.x & 63) == 0) wsum[threadIdx.x >> 6] = acc;
    __syncthreads();
    if (threadIdx.x == 0) {
        const float w = (ic == jc) ? 1.0f : 2.0f;
        partial[bid] = (wsum[0] + wsum[1] + wsum[2] + wsum[3]) * w;
    }
}

// Stage 2: reduce NBLOCKS partials, write the scaled scalar.
__global__ __launch_bounds__(NTHREADS)
void dirac_final_kernel(const float* __restrict__ partial,
                        float* __restrict__ out) {
    float v = 0.0f;
#pragma unroll
    for (int k = 0; k < (NBLOCKS + NTHREADS - 1) / NTHREADS; ++k) {
        const int idx = k * NTHREADS + threadIdx.x;
        if (idx < NBLOCKS) v += partial[idx];
    }

    for (int off = 32; off; off >>= 1)
        v += __shfl_down(v, off, 64);

    __shared__ float wsum[NTHREADS / 64];
    if ((threadIdx.x & 63) == 0) wsum[threadIdx.x >> 6] = v;
    __syncthreads();

    if (threadIdx.x == 0)
        out[0] = (wsum[0] + wsum[1] + wsum[2] + wsum[3]) * SCALE_F;
}

extern "C" void kernel_launch(void* const* d_in, const int* in_sizes, int n_in,
                              void* d_out, int out_size, void* d_ws, size_t ws_size,
                              hipStream_t stream) {
    const float* x = (const float*)d_in[0];   // input  [B, N] f32
    const float* t = (const float*)d_in[1];   // target [B, N] f32
    float* out     = (float*)d_out;           // scalar f32
    float* partial = (float*)d_ws;            // NBLOCKS floats of scratch

    dirac_partial_kernel<<<dim3(NBLOCKS), dim3(NTHREADS), 0, stream>>>(x, t, partial);
    dirac_final_kernel<<<dim3(1), dim3(NTHREADS), 0, stream>>>(partial, out);
}

// Round 5
// 66.608 us; speedup vs baseline: 1.1958x; 1.0221x over previous
//
#include <hip/hip_runtime.h>
#include <hip/hip_bf16.h>

// Problem constants (match the JAX reference exactly).
#define BATCH 4
#define NDIM  4096
#define TILE  128
#define TT    (NDIM / TILE)            // 32 tiles per dim
#define TRI   (TT * (TT + 1) / 2)      // 528 upper-triangle tiles per batch
#define NBLOCKS (BATCH * TRI)          // 2112
#define NTHREADS 256

#define A_CONST  (-0.565)
#define B_CONST  (4.0)
#define SQRT_PI  (1.772453851)

// exp(-(B*d/A)^2) = exp2( L * d*d ),  L = -(B/A)^2 * log2(e)
constexpr double K_D   = (B_CONST / A_CONST) * (B_CONST / A_CONST);
constexpr double LOG2E = 1.4426950408889634;
constexpr float  L_F   = (float)(-K_D * LOG2E);      // ~ -72.30994

// Overall scale: (1/(A*sqrt(pi)))^2 / (B*N*N) — the "+1" in dirac cancels.
constexpr double C2_D    = 1.0 / (A_CONST * A_CONST * SQRT_PI * SQRT_PI);
constexpr double NPAIRS  = (double)BATCH * (double)NDIM * (double)NDIM;
constexpr float  SCALE_F = (float)(C2_D / NPAIRS);

// Stage 1: one 128x128 tile of the symmetric pair matrix per block.
// Upper-triangle tiles only; off-diagonal tiles weighted x2, diagonal full x1
// (i==j diagonal contributes exactly 0). Irreducible cost: 2 v_exp_f32/pair.
__global__ __launch_bounds__(NTHREADS)
void dirac_partial_kernel(const float* __restrict__ x,
                          const float* __restrict__ t,
                          float* __restrict__ partial) {
    const int bid = blockIdx.x;
    const int b   = bid / TRI;
    int rr = bid % TRI;
    int ic = 0;                         // triangular index -> (ic, jc), jc >= ic
    while (rr >= TT - ic) { rr -= TT - ic; ++ic; }
    const int jc = ic + rr;

    const float* xb = x + b * NDIM;
    const float* tb = t + b * NDIM;

    // Per-j quad packed as float4 -> single broadcast ds_read_b128 per pair.
    __shared__ float4 sj[TILE];
    if (threadIdx.x < TILE) {
        const float xj = xb[jc * TILE + threadIdx.x];
        const float tj = tb[jc * TILE + threadIdx.x];
        sj[threadIdx.x] = make_float4(xj, L_F * xj * xj, tj, L_F * tj * tj);
    }
    __syncthreads();

    // 256 threads over 128 i's: 2 threads per i, each takes half the j range.
    const int il = threadIdx.x & (TILE - 1);
    const int i  = ic * TILE + il;
    const float xi = xb[i];
    const float ti = tb[i];
    const float ax = L_F * xi * xi;          // L*(u-v)^2 = ax + bx*v + c(v)
    const float bx = -2.0f * L_F * xi;
    const float at = L_F * ti * ti;
    const float bt = -2.0f * L_F * ti;

    const int jbase = (threadIdx.x >> 7) * (TILE / 2);   // 0 or 64, wave-uniform
    float acc0 = 0.0f, acc1 = 0.0f;          // two chains: break serial FMA dep
#pragma unroll 8
    for (int jj = 0; jj < TILE / 2; jj += 2) {
        const float4 v0 = sj[jbase + jj];
        const float4 v1 = sj[jbase + jj + 1];
        const float ep0 = __builtin_amdgcn_exp2f(fmaf(bx, v0.x, ax + v0.y));
        const float eg0 = __builtin_amdgcn_exp2f(fmaf(bt, v0.z, at + v0.w));
        const float ep1 = __builtin_amdgcn_exp2f(fmaf(bx, v1.x, ax + v1.y));
        const float eg1 = __builtin_amdgcn_exp2f(fmaf(bt, v1.z, at + v1.w));
        const float d0  = ep0 - eg0;
        const float d1  = ep1 - eg1;
        acc0 = fmaf(d0, d0, acc0);
        acc1 = fmaf(d1, d1, acc1);
    }
    float acc = acc0 + acc1;

    // Block reduce 256 -> 1.
    for (int off = 32; off; off >>= 1)
        acc += __shfl_down(acc, off, 64);
    __shared__ float wsum[NTHREADS / 64];
    if ((threadIdx.x & 63) == 0) wsum[threadIdx.x >> 6] = acc;
    __syncthreads();
    if (threadIdx.x == 0) {
        const float w = (ic == jc) ? 1.0f : 2.0f;
        partial[bid] = (wsum[0] + wsum[1] + wsum[2] + wsum[3]) * w;
    }
}

// Stage 2: reduce NBLOCKS partials, write the scaled scalar.
#define FTHREADS 512
__global__ __launch_bounds__(FTHREADS)
void dirac_final_kernel(const float* __restrict__ partial,
                        float* __restrict__ out) {
    float v = 0.0f;
#pragma unroll
    for (int k = 0; k < (NBLOCKS + FTHREADS - 1) / FTHREADS; ++k) {
        const int idx = k * FTHREADS + threadIdx.x;
        if (idx < NBLOCKS) v += partial[idx];
    }

    for (int off = 32; off; off >>= 1)
        v += __shfl_down(v, off, 64);

    __shared__ float wsum[FTHREADS / 64];
    if ((threadIdx.x & 63) == 0) wsum[threadIdx.x >> 6] = v;
    __syncthreads();

    if (threadIdx.x == 0) {
        float s = 0.0f;
#pragma unroll
        for (int k = 0; k < FTHREADS / 64; ++k) s += wsum[k];
        out[0] = s * SCALE_F;
    }
}

extern "C" void kernel_launch(void* const* d_in, const int* in_sizes, int n_in,
                              void* d_out, int out_size, void* d_ws, size_t ws_size,
                              hipStream_t stream) {
    const float* x = (const float*)d_in[0];   // input  [B, N] f32
    const float* t = (const float*)d_in[1];   // target [B, N] f32
    float* out     = (float*)d_out;           // scalar f32
    float* partial = (float*)d_ws;            // NBLOCKS floats of scratch

    dirac_partial_kernel<<<dim3(NBLOCKS), dim3(NTHREADS), 0, stream>>>(x, t, partial);
    dirac_final_kernel<<<dim3(1), dim3(FTHREADS), 0, stream>>>(partial, out);
}